// Round 10
// baseline (114.698 us; speedup 1.0000x reference)
//
#include <hip/hip_runtime.h>
#include <hip/hip_bf16.h>

// Problem constants (fixed by reference: LS = 8x l0 + 8x l1 + 4x l2)
#define D    52          // dim of in1/in2/out
#define DD   2704        // D*D
#define HH   2000        // cb height
#define DO   52          // output dim
#define KP   3328        // padded K for main GEMM = 52 * 64
#define NO   64          // padded output dim
#define KS   8           // K-split for main MFMA kernel
#define KT_TOTAL (KP/32) // 104
#define KT_PER   (KT_TOTAL/KS) // 13
#define MG   8           // K-split groups for M-precompute GEMM
#define KCH  256         // padded K per group (8*256 = 2048 >= 2000)
#define WHP  2048        // padded W row length

typedef __attribute__((ext_vector_type(8))) short short8;
typedef __attribute__((ext_vector_type(4))) float f32x4;

// ws layout (bytes)
#define WB_OFF     0
#define WB_BYTES   (NO * WHP * 2)              //    262,144
#define MTP_OFF    (WB_OFF + WB_BYTES)
#define MTP_BYTES  (MG * NO * DD * 4)          //  5,537,792
#define MTB_OFF    (MTP_OFF + MTP_BYTES)
#define MTB_BYTES  (KT_TOTAL * NO * 32 * 2)    //    425,984
#define OUTP_OFF   (MTB_OFF + MTB_BYTES)
#define OUTP_BYTES (KS * 4096 * NO * 4)        //  8,388,608

static __device__ __forceinline__ unsigned short f2bf(float f) {
    __hip_bfloat16 h = __float2bfloat16(f);
    return __builtin_bit_cast(unsigned short, h);
}

// ---------------------------------------------------------------------------
// K_A: pack W -> bf16, zero-padded: Wb[o][h], o<64, h<2048
// ---------------------------------------------------------------------------
__global__ __launch_bounds__(256) void k_packw(
    const float* __restrict__ W, unsigned short* __restrict__ Wb) {
    int idx = blockIdx.x * 256 + threadIdx.x;
    if (idx >= NO * WHP) return;
    int o = idx >> 11, h = idx & (WHP - 1);
    float v = (o < DO && h < HH) ? W[o * HH + h] : 0.f;
    Wb[idx] = f2bf(v);
}

// ---------------------------------------------------------------------------
// K_B: M-precompute via MFMA.  mtp[g][o][ij] = sum_{h in grp g} W[o,h]*cb[h,ij]
// A = W (M=o), B = cb-tile (N=ij).  (verified round 6)
// ---------------------------------------------------------------------------
__global__ __launch_bounds__(256) void k_mgemm(
    const float* __restrict__ cb, const unsigned short* __restrict__ Wb,
    float* __restrict__ mtp) {
    __shared__ float shAT[64][33];   // [ij_local][h_local], stride 33 -> 2-way max
    int lane = threadIdx.x & 63;
    int w    = __builtin_amdgcn_readfirstlane(threadIdx.x >> 6);
    int r    = lane & 15;
    int kg   = lane >> 4;
    int ij0  = blockIdx.x * 64;
    int g    = blockIdx.y;

    f32x4 acc[4];
#pragma unroll
    for (int mt = 0; mt < 4; ++mt) acc[mt] = (f32x4){0.f, 0.f, 0.f, 0.f};

    int srow = threadIdx.x >> 6;       // 0..3
    int scol = threadIdx.x & 63;       // ij offset
    int sij  = ij0 + scol;
    bool ijv = (sij < DD);

#pragma unroll
    for (int kt = 0; kt < KCH / 32; ++kt) {
        int h0 = g * KCH + kt * 32;
        __syncthreads();   // previous reads done before overwrite
#pragma unroll
        for (int p = 0; p < 8; ++p) {
            int row = srow + p * 4;                 // h_local 0..31
            int h = h0 + row;
            float v = (h < HH && ijv) ? cb[(size_t)h * DD + sij] : 0.f;
            shAT[scol][row] = v;
        }
        __syncthreads();

        // B-frag (cb): b[e] = B[k=kg*8+e][n=ij], wave owns ij = ij0+w*16+r
        short8 bf;
#pragma unroll
        for (int e = 0; e < 8; ++e)
            bf[e] = (short)f2bf(shAT[w * 16 + r][kg * 8 + e]);
        // A-frags (W): a[e] = Wb[o][h], o = mt*16+r, contiguous 16B
#pragma unroll
        for (int mt = 0; mt < 4; ++mt) {
            short8 a = *reinterpret_cast<const short8*>(
                Wb + (size_t)(mt * 16 + r) * WHP + g * KCH + kt * 32 + kg * 8);
            acc[mt] = __builtin_amdgcn_mfma_f32_16x16x32_bf16(a, bf, acc[mt], 0, 0, 0);
        }
    }

    // D layout: col(lane&15) = n = ij, row(kg*4+q) = m = o
    int ij = ij0 + w * 16 + r;
    if (ij < DD) {
#pragma unroll
        for (int mt = 0; mt < 4; ++mt) {
#pragma unroll
            for (int q = 0; q < 4; ++q) {
                int o = mt * 16 + kg * 4 + q;
                mtp[((size_t)g * NO + o) * DD + ij] = acc[mt][q];
            }
        }
    }
}

// ---------------------------------------------------------------------------
// K_C: reduce partials over g + pack blocked-B bf16:
//   mtB[kt][o][kg][e] = bf16( M[o, i*52+j] ),  k = i*64+j (padded, j>=52 -> 0)
// ---------------------------------------------------------------------------
__global__ __launch_bounds__(256) void k_reduce_mtb(
    const float* __restrict__ mtp, unsigned short* __restrict__ mtB) {
    int k = blockIdx.x * 256 + threadIdx.x;   // 0..3327 (= KP exactly)
    int o = blockIdx.y;
    int i = k >> 6, j = k & 63;
    float s = 0.f;
    if (j < D) {
        size_t base = (size_t)o * DD + i * D + j;
#pragma unroll
        for (int g = 0; g < MG; ++g) s += mtp[(size_t)g * (NO * DD) + base];
    }
    mtB[((size_t)(k >> 5) * NO + o) * 32 + ((k >> 3) & 3) * 8 + (k & 7)] = f2bf(s);
}

// ---------------------------------------------------------------------------
// K_D: MFMA main: outp[ks][b][o] = sum_{k in split ks} outer_bf16[b,k]*M[o,k]
// v3: block = 64 batches (4 waves x 16); each wave computes ALL 4 o-tiles
// (4 accs) -> A-build + LDS reads amortized 4x. sh2 stride 72: rows 16B-
// aligned -> ds_read_b128 pairs; banks 4 groups x 8 -> <=2-way (free).
// ---------------------------------------------------------------------------
__global__ __launch_bounds__(256) void k_main_mfma(
    const float* __restrict__ in1, const float* __restrict__ in2,
    const unsigned short* __restrict__ mtB, float* __restrict__ outp) {
    __shared__ float sh1[64][53];
    __shared__ float sh2[64][72];

    int lane = threadIdx.x & 63;
    int w    = __builtin_amdgcn_readfirstlane(threadIdx.x >> 6);
    int b0   = blockIdx.x * 64;
    int ks   = blockIdx.y;
    int r    = lane & 15;
    int kg   = lane >> 4;

    // stage: float4 global loads, scalar LDS stores (rows are 16B-aligned)
    for (int t = threadIdx.x; t < 64 * 13; t += 256) {
        int row = t / 13, q = t - row * 13;
        float4 v = *reinterpret_cast<const float4*>(in2 + (size_t)(b0 + row) * D + 4 * q);
        sh2[row][4 * q + 0] = v.x; sh2[row][4 * q + 1] = v.y;
        sh2[row][4 * q + 2] = v.z; sh2[row][4 * q + 3] = v.w;
    }
    for (int t = threadIdx.x; t < 64 * 12; t += 256) {   // zero-pad j = 52..63
        int row = t / 12, j = 52 + (t - row * 12);
        sh2[row][j] = 0.f;
    }
    for (int t = threadIdx.x; t < 64 * 13; t += 256) {
        int row = t / 13, q = t - row * 13;
        float4 v = *reinterpret_cast<const float4*>(in1 + (size_t)(b0 + row) * D + 4 * q);
        sh1[row][4 * q + 0] = v.x; sh1[row][4 * q + 1] = v.y;
        sh1[row][4 * q + 2] = v.z; sh1[row][4 * q + 3] = v.w;
    }
    __syncthreads();

    int mrow = w * 16 + r;   // this lane's batch row (A m-index)
    f32x4 acc[4];
#pragma unroll
    for (int nt = 0; nt < 4; ++nt) acc[nt] = (f32x4){0.f, 0.f, 0.f, 0.f};

    const unsigned short* bbase =
        mtB + ((size_t)(ks * KT_PER) * NO + r) * 32 + kg * 8;

#pragma unroll 4
    for (int t = 0; t < KT_PER; ++t) {
        int kt   = ks * KT_PER + t;
        int i    = kt >> 1;
        int j0   = (kt & 1) * 32 + kg * 8;
        float f1 = sh1[mrow][i];
        float4 v0 = *reinterpret_cast<const float4*>(&sh2[mrow][j0]);
        float4 v1 = *reinterpret_cast<const float4*>(&sh2[mrow][j0 + 4]);
        short8 a;
        a[0] = (short)f2bf(f1 * v0.x); a[1] = (short)f2bf(f1 * v0.y);
        a[2] = (short)f2bf(f1 * v0.z); a[3] = (short)f2bf(f1 * v0.w);
        a[4] = (short)f2bf(f1 * v1.x); a[5] = (short)f2bf(f1 * v1.y);
        a[6] = (short)f2bf(f1 * v1.z); a[7] = (short)f2bf(f1 * v1.w);
#pragma unroll
        for (int nt = 0; nt < 4; ++nt) {
            short8 b = *reinterpret_cast<const short8*>(
                bbase + ((size_t)t * NO + nt * 16) * 32);
            acc[nt] = __builtin_amdgcn_mfma_f32_16x16x32_bf16(a, b, acc[nt], 0, 0, 0);
        }
    }

    // C/D: col = r -> o = nt*16+r;  row = kg*4+q -> batch = b0 + w*16 + kg*4+q
#pragma unroll
    for (int nt = 0; nt < 4; ++nt) {
#pragma unroll
        for (int q = 0; q < 4; ++q) {
            outp[((size_t)ks * 4096 + b0 + w * 16 + kg * 4 + q) * NO + nt * 16 + r]
                = acc[nt][q];
        }
    }
}

// ---------------------------------------------------------------------------
// K_E: out[b][o] = sum_ks outp[ks][b][o]
// ---------------------------------------------------------------------------
__global__ __launch_bounds__(256) void k_out(
    const float* __restrict__ outp, float* __restrict__ out, int B) {
    int idx = blockIdx.x * 256 + threadIdx.x;
    if (idx >= B * DO) return;
    int b = idx / DO, o = idx - b * DO;
    float s = 0.f;
#pragma unroll
    for (int g = 0; g < KS; ++g) s += outp[((size_t)g * B + b) * NO + o];
    out[idx] = s;
}

// ---------------------------------------------------------------------------
extern "C" void kernel_launch(void* const* d_in, const int* in_sizes, int n_in,
                              void* d_out, int out_size, void* d_ws, size_t ws_size,
                              hipStream_t stream) {
    const float* in1 = (const float*)d_in[0];
    const float* in2 = (const float*)d_in[1];
    const float* cb  = (const float*)d_in[2];
    const float* W   = (const float*)d_in[3];
    float* out = (float*)d_out;

    int B = in_sizes[0] / D;  // 4096

    char* ws = (char*)d_ws;
    unsigned short* Wb   = (unsigned short*)(ws + WB_OFF);
    float*          mtp  = (float*)(ws + MTP_OFF);
    unsigned short* mtB  = (unsigned short*)(ws + MTB_OFF);
    float*          outp = (float*)(ws + OUTP_OFF);

    hipLaunchKernelGGL(k_packw, dim3((NO * WHP + 255) / 256), dim3(256), 0,
                       stream, W, Wb);
    hipLaunchKernelGGL(k_mgemm, dim3((DD + 63) / 64, MG), dim3(256), 0,
                       stream, cb, Wb, mtp);
    hipLaunchKernelGGL(k_reduce_mtb, dim3(KP / 256, NO), dim3(256), 0,
                       stream, mtp, mtB);
    hipLaunchKernelGGL(k_main_mfma, dim3(B / 64, KS), dim3(256), 0,
                       stream, in1, in2, mtB, outp);
    hipLaunchKernelGGL(k_out, dim3((B * DO + 255) / 256), dim3(256), 0,
                       stream, outp, out, B);
}

// Round 11
// 101.152 us; speedup vs baseline: 1.1339x; 1.1339x over previous
//
#include <hip/hip_runtime.h>
#include <hip/hip_bf16.h>

// Problem constants (fixed by reference: LS = 8x l0 + 8x l1 + 4x l2)
#define D    52          // dim of in1/in2/out
#define DD   2704        // D*D
#define HH   2000        // cb height
#define DO   52          // output dim
#define KP   3328        // padded K for main GEMM = 52 * 64
#define NO   64          // padded output dim
#define KT_TOTAL (KP/32) // 104 MFMA k-steps
#define KT_W   (KT_TOTAL/8) // 13 k-steps per wave in fused main
#define MG   16          // K-split groups for M-precompute GEMM
#define KCH  128         // padded K per group (16*128 = 2048 >= 2000)
#define WHP  2048        // padded W row length

typedef __attribute__((ext_vector_type(8))) short short8;
typedef __attribute__((ext_vector_type(4))) float f32x4;

// ws layout (bytes)
#define WB_OFF     0
#define WB_BYTES   (NO * WHP * 2)              //    262,144
#define MTP_OFF    (WB_OFF + WB_BYTES)
#define MTP_BYTES  (MG * NO * DD * 4)          // 11,075,584
#define MTB_OFF    (MTP_OFF + MTP_BYTES)
#define MTB_BYTES  (KT_TOTAL * NO * 32 * 2)    //    425,984

static __device__ __forceinline__ unsigned short f2bf(float f) {
    __hip_bfloat16 h = __float2bfloat16(f);
    return __builtin_bit_cast(unsigned short, h);
}

// ---------------------------------------------------------------------------
// K_A: pack W -> bf16, zero-padded: Wb[o][h], o<64, h<2048   (round-4, verified)
// ---------------------------------------------------------------------------
__global__ __launch_bounds__(256) void k_packw(
    const float* __restrict__ W, unsigned short* __restrict__ Wb) {
    int idx = blockIdx.x * 256 + threadIdx.x;
    if (idx >= NO * WHP) return;
    int o = idx >> 11, h = idx & (WHP - 1);
    float v = (o < DO && h < HH) ? W[o * HH + h] : 0.f;
    Wb[idx] = f2bf(v);
}

// ---------------------------------------------------------------------------
// K_B: M-precompute via MFMA.  mtp[g][o][ij] = sum_{h in grp g} W[o,h]*cb[h,ij]
// A = W (M=o), B = cb-tile (N=ij).  (round-4 version, measured in 106.6 run)
// ---------------------------------------------------------------------------
__global__ __launch_bounds__(256) void k_mgemm(
    const float* __restrict__ cb, const unsigned short* __restrict__ Wb,
    float* __restrict__ mtp) {
    __shared__ float shAT[64][33];   // [ij_local][h_local], stride 33 -> 2-way max
    int lane = threadIdx.x & 63;
    int w    = __builtin_amdgcn_readfirstlane(threadIdx.x >> 6);
    int r    = lane & 15;
    int kg   = lane >> 4;
    int ij0  = blockIdx.x * 64;
    int g    = blockIdx.y;

    f32x4 acc[4];
#pragma unroll
    for (int mt = 0; mt < 4; ++mt) acc[mt] = (f32x4){0.f, 0.f, 0.f, 0.f};

    int srow = threadIdx.x >> 6;       // 0..3
    int scol = threadIdx.x & 63;       // ij offset
    int sij  = ij0 + scol;
    bool ijv = (sij < DD);

#pragma unroll
    for (int kt = 0; kt < KCH / 32; ++kt) {
        int h0 = g * KCH + kt * 32;
        __syncthreads();   // previous reads done before overwrite
#pragma unroll
        for (int p = 0; p < 8; ++p) {
            int row = srow + p * 4;                 // h_local 0..31
            int h = h0 + row;
            float v = (h < HH && ijv) ? cb[(size_t)h * DD + sij] : 0.f;
            shAT[scol][row] = v;
        }
        __syncthreads();

        // B-frag (cb): b[e] = B[k=kg*8+e][n=ij], wave owns ij = ij0+w*16+r
        short8 bf;
#pragma unroll
        for (int e = 0; e < 8; ++e)
            bf[e] = (short)f2bf(shAT[w * 16 + r][kg * 8 + e]);
        // A-frags (W): a[e] = Wb[o][h], o = mt*16+r, contiguous 16B
#pragma unroll
        for (int mt = 0; mt < 4; ++mt) {
            short8 a = *reinterpret_cast<const short8*>(
                Wb + (size_t)(mt * 16 + r) * WHP + g * KCH + kt * 32 + kg * 8);
            acc[mt] = __builtin_amdgcn_mfma_f32_16x16x32_bf16(a, bf, acc[mt], 0, 0, 0);
        }
    }

    // D layout: col(lane&15) = n = ij, row(kg*4+q) = m = o
    int ij = ij0 + w * 16 + r;
    if (ij < DD) {
#pragma unroll
        for (int mt = 0; mt < 4; ++mt) {
#pragma unroll
            for (int q = 0; q < 4; ++q) {
                int o = mt * 16 + kg * 4 + q;
                mtp[((size_t)g * NO + o) * DD + ij] = acc[mt][q];
            }
        }
    }
}

// ---------------------------------------------------------------------------
// K_C: reduce partials over g + pack blocked-B bf16:
//   mtB[kt][o][kg][e] = bf16( M[o, i*52+j] ),  k = i*64+j (padded, j>=52 -> 0)
// (round-4 version)
// ---------------------------------------------------------------------------
__global__ __launch_bounds__(256) void k_reduce_mtb(
    const float* __restrict__ mtp, unsigned short* __restrict__ mtB) {
    int k = blockIdx.x * 256 + threadIdx.x;   // 0..3327 (= KP exactly)
    int o = blockIdx.y;
    int i = k >> 6, j = k & 63;
    float s = 0.f;
    if (j < D) {
        size_t base = (size_t)o * DD + i * D + j;
#pragma unroll
        for (int g = 0; g < MG; ++g) s += mtp[(size_t)g * (NO * DD) + base];
    }
    mtB[((size_t)(k >> 5) * NO + o) * 32 + ((k >> 3) & 3) * 8 + (k & 7)] = f2bf(s);
}

// ---------------------------------------------------------------------------
// K_D: fused main. block = 512 thr (8 waves) x 16 batch rows; wave w owns
// K-eighth (13 kt), computes ALL 4 o-tiles (A-build amortized 4x, verified
// fragment mapping); cross-wave K-reduce in LDS; writes d_out directly.
// No outp buffer, no k_out dispatch.
// ---------------------------------------------------------------------------
__global__ __launch_bounds__(512) void k_main_fused(
    const float* __restrict__ in1, const float* __restrict__ in2,
    const unsigned short* __restrict__ mtB, float* __restrict__ out) {
    __shared__ float sh1[16][53];
    __shared__ float sh2[16][72];
    __shared__ float red[8][16][64];

    int tid  = threadIdx.x;
    int lane = tid & 63;
    int w    = __builtin_amdgcn_readfirstlane(tid >> 6);  // 0..7
    int r    = lane & 15;
    int kg   = lane >> 4;
    int b0   = blockIdx.x * 16;

    // stage 16 rows of in1/in2 (rows are 208 B -> 16B-aligned float4)
    for (int t = tid; t < 16 * 13; t += 512) {
        int row = t / 13, q = t - row * 13;
        float4 v = *reinterpret_cast<const float4*>(in2 + (size_t)(b0 + row) * D + 4 * q);
        sh2[row][4 * q + 0] = v.x; sh2[row][4 * q + 1] = v.y;
        sh2[row][4 * q + 2] = v.z; sh2[row][4 * q + 3] = v.w;
    }
    for (int t = tid; t < 16 * 12; t += 512) {   // zero-pad j = 52..63
        int row = t / 12, j = 52 + (t - row * 12);
        sh2[row][j] = 0.f;
    }
    for (int t = tid; t < 16 * 13; t += 512) {
        int row = t / 13, q = t - row * 13;
        float4 v = *reinterpret_cast<const float4*>(in1 + (size_t)(b0 + row) * D + 4 * q);
        sh1[row][4 * q + 0] = v.x; sh1[row][4 * q + 1] = v.y;
        sh1[row][4 * q + 2] = v.z; sh1[row][4 * q + 3] = v.w;
    }
    __syncthreads();

    f32x4 acc[4];
#pragma unroll
    for (int nt = 0; nt < 4; ++nt) acc[nt] = (f32x4){0.f, 0.f, 0.f, 0.f};

    const unsigned short* bbase =
        mtB + ((size_t)(w * KT_W) * NO + r) * 32 + kg * 8;

#pragma unroll
    for (int t = 0; t < KT_W; ++t) {
        int kt   = w * KT_W + t;
        int i    = kt >> 1;
        int j0   = (kt & 1) * 32 + kg * 8;
        float f1 = sh1[r][i];
        float4 v0 = *reinterpret_cast<const float4*>(&sh2[r][j0]);
        float4 v1 = *reinterpret_cast<const float4*>(&sh2[r][j0 + 4]);
        short8 a;
        a[0] = (short)f2bf(f1 * v0.x); a[1] = (short)f2bf(f1 * v0.y);
        a[2] = (short)f2bf(f1 * v0.z); a[3] = (short)f2bf(f1 * v0.w);
        a[4] = (short)f2bf(f1 * v1.x); a[5] = (short)f2bf(f1 * v1.y);
        a[6] = (short)f2bf(f1 * v1.z); a[7] = (short)f2bf(f1 * v1.w);
#pragma unroll
        for (int nt = 0; nt < 4; ++nt) {
            short8 b = *reinterpret_cast<const short8*>(
                bbase + ((size_t)t * NO + nt * 16) * 32);
            acc[nt] = __builtin_amdgcn_mfma_f32_16x16x32_bf16(a, b, acc[nt], 0, 0, 0);
        }
    }

    // C/D: col = r -> o = nt*16+r; row = kg*4+q -> batch row within tile
#pragma unroll
    for (int nt = 0; nt < 4; ++nt) {
#pragma unroll
        for (int q = 0; q < 4; ++q) {
            red[w][kg * 4 + q][nt * 16 + r] = acc[nt][q];
        }
    }
    __syncthreads();

    // cross-wave K-reduction + direct output write
    for (int idx = tid; idx < 16 * 64; idx += 512) {
        int row = idx >> 6, o = idx & 63;
        float s = 0.f;
#pragma unroll
        for (int ww = 0; ww < 8; ++ww) s += red[ww][row][o];
        if (o < DO) out[(size_t)(b0 + row) * DO + o] = s;
    }
}

// ---------------------------------------------------------------------------
extern "C" void kernel_launch(void* const* d_in, const int* in_sizes, int n_in,
                              void* d_out, int out_size, void* d_ws, size_t ws_size,
                              hipStream_t stream) {
    const float* in1 = (const float*)d_in[0];
    const float* in2 = (const float*)d_in[1];
    const float* cb  = (const float*)d_in[2];
    const float* W   = (const float*)d_in[3];
    float* out = (float*)d_out;

    int B = in_sizes[0] / D;  // 4096

    char* ws = (char*)d_ws;
    unsigned short* Wb  = (unsigned short*)(ws + WB_OFF);
    float*          mtp = (float*)(ws + MTP_OFF);
    unsigned short* mtB = (unsigned short*)(ws + MTB_OFF);

    hipLaunchKernelGGL(k_packw, dim3((NO * WHP + 255) / 256), dim3(256), 0,
                       stream, W, Wb);
    hipLaunchKernelGGL(k_mgemm, dim3((DD + 63) / 64, MG), dim3(256), 0,
                       stream, cb, Wb, mtp);
    hipLaunchKernelGGL(k_reduce_mtb, dim3(KP / 256, NO), dim3(256), 0,
                       stream, mtp, mtB);
    hipLaunchKernelGGL(k_main_fused, dim3(B / 16), dim3(512), 0,
                       stream, in1, in2, mtB, out);
}